// Round 7
// baseline (357.741 us; speedup 1.0000x reference)
//
#include <hip/hip_runtime.h>

// DepthwiseConv3D: x(8,64,64,32,64) fp32, w(32,3,3,64), b(32,64)
// y[b,h,w,d,c] = sum_{kh,kw} x[b,h+kh-1,w+kw-1,d,c]*w[d,kh,kw,c] + b[d,c]
// float4 strides: c4=1, d=16, w=512, h=32768, b=2097152
//
// R7: 512-thread blocks carrying the FULL (d,c) slab (32 d x 64 c = 8 KB
// contiguous per (h,w) pixel). Per row a block reads a 48 KB contiguous
// run (6 w-cols) and writes a 32 KB run -> long DRAM-page-friendly
// streams instead of R5's interleaved 1 KB half-slab accesses.
// Per-thread tile unchanged: 4h x 4w, 36 hoisted loads (2.25 taps/out).
// XCD-chunked swizzle kept: b = blk&7 (one batch per XCD), h4-major /
// ws-minor in-chunk (6-row halo window = 3 MB < 4 MiB per-XCD L2,
// w-halos hit L2 from the adjacent ws block).

typedef float v4 __attribute__((ext_vector_type(4)));

__global__ __launch_bounds__(512, 4) void DepthwiseConv3D_kernel(
    const v4* __restrict__ x, const v4* __restrict__ wgt,
    const v4* __restrict__ bias, v4* __restrict__ y) {
  // Block: b = blk&7 (XCD id); loc = blk>>3: ws = loc&15, h4 = loc>>4
  const int blk = blockIdx.x;
  const int b   = blk & 7;
  const int loc = blk >> 3;
  const int ws  = loc & 15;
  const int h4  = loc >> 4;          // 0..15
  // Thread: c4 = t&15, d = t>>4 (full 0..31)
  const int c4  = threadIdx.x & 15;
  const int d   = threadIdx.x >> 4;
  const int h   = h4 * 4;
  const int w0  = ws * 4;

  const int base = ((b * 64 + h) * 64) * 512 + d * 16 + c4;  // (b,h,0,d,c4)
  const bool rtop = (h4 > 0);   // row h-1 exists
  const bool rbot = (h4 < 15);  // row h+4 exists
  const v4 z = (v4)(0.f);

  // Hoist all 36 x-loads (6 w-cols x 6 h-rows: h-1 .. h+4).
  v4 col[6][6];
#pragma unroll
  for (int j = 0; j < 6; ++j) {
    const int wc = w0 - 1 + j;
    const bool wok = ((unsigned)wc) < 64u;
    const int p = base + wc * 512;
    col[j][0] = (wok && rtop) ? x[p - 32768] : z;
#pragma unroll
    for (int r = 1; r < 5; ++r)
      col[j][r] = wok ? x[p + (r - 1) * 32768] : z;
    col[j][5] = (wok && rbot) ? x[p + 131072] : z;
  }

  // Weights/bias after x-loads (L2-resident, cheap).
  v4 wt[3][3];
#pragma unroll
  for (int kh = 0; kh < 3; ++kh)
#pragma unroll
    for (int kw = 0; kw < 3; ++kw)
      wt[kh][kw] = wgt[d * 144 + kh * 48 + kw * 16 + c4];
  const v4 bv = bias[d * 16 + c4];

  v4 acc[4][4];
#pragma unroll
  for (int hh = 0; hh < 4; ++hh)
#pragma unroll
    for (int i = 0; i < 4; ++i) acc[hh][i] = bv;

#pragma unroll
  for (int kh = 0; kh < 3; ++kh)
#pragma unroll
    for (int kw = 0; kw < 3; ++kw)
#pragma unroll
      for (int hh = 0; hh < 4; ++hh)
#pragma unroll
        for (int i = 0; i < 4; ++i)
          acc[hh][i] += col[i + kw][hh + kh] * wt[kh][kw];

  // Nontemporal: y never re-read; keep L2/L3 for x.
#pragma unroll
  for (int hh = 0; hh < 4; ++hh)
#pragma unroll
    for (int i = 0; i < 4; ++i)
      __builtin_nontemporal_store(acc[hh][i],
                                  &y[base + hh * 32768 + (w0 + i) * 512]);
}

extern "C" void kernel_launch(void* const* d_in, const int* in_sizes, int n_in,
                              void* d_out, int out_size, void* d_ws, size_t ws_size,
                              hipStream_t stream) {
  const v4* x    = (const v4*)d_in[0];
  const v4* wgt  = (const v4*)d_in[1];
  const v4* bias = (const v4*)d_in[2];
  v4* y          = (v4*)d_out;
  // 8 XCDs x 256 blocks (16 h4 x 16 ws per batch), 512 threads each
  DepthwiseConv3D_kernel<<<2048, 512, 0, stream>>>(x, wgt, bias, y);
}

// Round 8
// 90.685 us; speedup vs baseline: 3.9449x; 3.9449x over previous
//
#include <hip/hip_runtime.h>

// DepthwiseConv3D: x(8,64,64,32,64) fp32, w(32,3,3,64), b(32,64)
// y[b,h,w,d,c] = sum_{kh,kw} x[b,h+kh-1,w+kw-1,d,c]*w[d,kh,kw,c] + b[d,c]
// float4 strides: c4=1, d=16, w=512, h=32768, b=2097152
//
// R8 = R7 (full-slab 512-thread blocks, 48 KB contiguous read runs /
// 32 KB write runs per row) with the register budget FIXED:
// launch_bounds(512,2) instead of (512,4). R7's (512,4) capped VGPR at
// 64 -> the 36-float4 window spilled to scratch (WRITE 256->911 MiB).
// Per-thread tile: 4h x 4w, 36 hoisted loads (2.25 taps/out).
// XCD-chunked swizzle: b = blk&7, h4-major / ws-minor.

typedef float v4 __attribute__((ext_vector_type(4)));

__global__ __launch_bounds__(512, 2) void DepthwiseConv3D_kernel(
    const v4* __restrict__ x, const v4* __restrict__ wgt,
    const v4* __restrict__ bias, v4* __restrict__ y) {
  // Block: b = blk&7 (XCD id); loc = blk>>3: ws = loc&15, h4 = loc>>4
  const int blk = blockIdx.x;
  const int b   = blk & 7;
  const int loc = blk >> 3;
  const int ws  = loc & 15;
  const int h4  = loc >> 4;          // 0..15
  // Thread: c4 = t&15, d = t>>4 (full 0..31)
  const int c4  = threadIdx.x & 15;
  const int d   = threadIdx.x >> 4;
  const int h   = h4 * 4;
  const int w0  = ws * 4;

  const int base = ((b * 64 + h) * 64) * 512 + d * 16 + c4;  // (b,h,0,d,c4)
  const bool rtop = (h4 > 0);   // row h-1 exists
  const bool rbot = (h4 < 15);  // row h+4 exists
  const v4 z = (v4)(0.f);

  // Hoist all 36 x-loads (6 w-cols x 6 h-rows: h-1 .. h+4).
  v4 col[6][6];
#pragma unroll
  for (int j = 0; j < 6; ++j) {
    const int wc = w0 - 1 + j;
    const bool wok = ((unsigned)wc) < 64u;
    const int p = base + wc * 512;
    col[j][0] = (wok && rtop) ? x[p - 32768] : z;
#pragma unroll
    for (int r = 1; r < 5; ++r)
      col[j][r] = wok ? x[p + (r - 1) * 32768] : z;
    col[j][5] = (wok && rbot) ? x[p + 131072] : z;
  }

  // Weights/bias after x-loads (L2-resident, cheap).
  v4 wt[3][3];
#pragma unroll
  for (int kh = 0; kh < 3; ++kh)
#pragma unroll
    for (int kw = 0; kw < 3; ++kw)
      wt[kh][kw] = wgt[d * 144 + kh * 48 + kw * 16 + c4];
  const v4 bv = bias[d * 16 + c4];

  v4 acc[4][4];
#pragma unroll
  for (int hh = 0; hh < 4; ++hh)
#pragma unroll
    for (int i = 0; i < 4; ++i) acc[hh][i] = bv;

#pragma unroll
  for (int kh = 0; kh < 3; ++kh)
#pragma unroll
    for (int kw = 0; kw < 3; ++kw)
#pragma unroll
      for (int hh = 0; hh < 4; ++hh)
#pragma unroll
        for (int i = 0; i < 4; ++i)
          acc[hh][i] += col[i + kw][hh + kh] * wt[kh][kw];

  // Nontemporal: y never re-read; keep L2/L3 for x.
#pragma unroll
  for (int hh = 0; hh < 4; ++hh)
#pragma unroll
    for (int i = 0; i < 4; ++i)
      __builtin_nontemporal_store(acc[hh][i],
                                  &y[base + hh * 32768 + (w0 + i) * 512]);
}

extern "C" void kernel_launch(void* const* d_in, const int* in_sizes, int n_in,
                              void* d_out, int out_size, void* d_ws, size_t ws_size,
                              hipStream_t stream) {
  const v4* x    = (const v4*)d_in[0];
  const v4* wgt  = (const v4*)d_in[1];
  const v4* bias = (const v4*)d_in[2];
  v4* y          = (v4*)d_out;
  // 8 XCDs x 256 blocks (16 h4 x 16 ws per batch), 512 threads each
  DepthwiseConv3D_kernel<<<2048, 512, 0, stream>>>(x, wgt, bias, y);
}